// Round 12
// baseline (696.559 us; speedup 1.0000x reference)
//
#include <hip/hip_runtime.h>
#include <cstdint>
#include <cstddef>

#define D       512
#define NROWS   16384
#define NCODES  8192
#define BM      128
#define BN      128
#define NKC     16              // K-tiles (BK=32 each)
#define NBLK    8192            // (16384/128)*(8192/128)
#define EPS     0.64f           // 2B: covers dropped xl*e term at ~6 sigma
#define RCB     1024
#define XTILE_B 8192            // packed x per (blk128,kc): HI only
#define ETILE_B 16384           // packed e per (blk128,kc): [HI 8KB][LO 8KB]
#define NC32    (NCODES / 32)   // 256 chunk-min entries per row

typedef __attribute__((ext_vector_type(8))) short short8;  // 8 bf16
typedef __attribute__((ext_vector_type(4))) float f32x4;
typedef unsigned long long u64;
typedef __attribute__((address_space(3))) uint32_t as3_u32;
typedef __attribute__((address_space(1))) uint32_t as1_u32;

// order-preserving fp32 <-> u32 key
__device__ __forceinline__ uint32_t fkey(float f) {
  uint32_t u = __float_as_uint(f);
  return (u & 0x80000000u) ? ~u : (u | 0x80000000u);
}
__device__ __forceinline__ float unfkey(uint32_t k) {
  uint32_t u = (k & 0x80000000u) ? (k & 0x7FFFFFFFu) : ~k;
  return __uint_as_float(u);
}
// round-to-nearest bf16, returned as high-aligned fp32 bits
__device__ __forceinline__ uint32_t bfhi(float f) {
  uint32_t u = __float_as_uint(f);
  return (u + 0x7FFFu + ((u >> 16) & 1u)) & 0xFFFF0000u;
}

// ---------------------------------------------------------------------------
// Pre-pack, output-address-ordered.  x -> HI plane only; e -> HI + LO.
// Chunk (r, cp) at byte r*64 + cp*16 within a plane; cp = c ^ ((r>>1)&3).
// ---------------------------------------------------------------------------
__global__ __launch_bounds__(256) void vq_pack_kernel(
    const float* __restrict__ x, const float* __restrict__ embed,
    uint32_t* __restrict__ px, uint32_t* __restrict__ pe) {
  const int oid  = blockIdx.x * 256 + threadIdx.x;
  const bool isX = oid < NROWS * 64;        // block-uniform split
  const int tt   = isX ? oid : oid - NROWS * 64;
  const float* src = isX ? x : embed;

  const int tile   = tt >> 9;        // (blk,kc): 512 chunks each
  const int within = tt & 511;       // = r*4 + cp
  const int blk = tile >> 4, kc = tile & 15;
  const int r   = within >> 2, cpp = within & 3;
  const int c   = cpp ^ ((r >> 1) & 3);     // source k-quarter

  const float* sp = src + (size_t)(blk * 128 + r) * D + kc * 32 + c * 8;
  const float4 v0 = *(const float4*)sp;
  const float4 v1 = *(const float4*)(sp + 4);
  const float f[8] = {v0.x, v0.y, v0.z, v0.w, v1.x, v1.y, v1.z, v1.w};
  uint32_t hi[4], lo[4];
#pragma unroll
  for (int p = 0; p < 4; ++p) {
    const uint32_t h0 = bfhi(f[2 * p]), h1 = bfhi(f[2 * p + 1]);
    hi[p] = (h0 >> 16) | (h1 & 0xFFFF0000u);
    const float l0 = f[2 * p] - __uint_as_float(h0);
    const float l1 = f[2 * p + 1] - __uint_as_float(h1);
    lo[p] = (bfhi(l0) >> 16) | (bfhi(l1) & 0xFFFF0000u);
  }
  if (isX) {
    uint32_t* dp = px + (size_t)tile * 2048 + within * 4;   // 8 KB tiles
    *(uint4*)dp = make_uint4(hi[0], hi[1], hi[2], hi[3]);
  } else {
    uint32_t* dp = pe + (size_t)tile * 4096 + within * 4;   // 16 KB tiles
    *(uint4*)dp          = make_uint4(hi[0], hi[1], hi[2], hi[3]);
    *(uint4*)(dp + 2048) = make_uint4(lo[0], lo[1], lo[2], lo[3]);
  }
}

// ---------------------------------------------------------------------------
__global__ void vq_e2_kernel(const float* __restrict__ embed,
                             float* __restrict__ e2) {
  const int w    = (blockIdx.x * blockDim.x + threadIdx.x) >> 6;
  const int lane = threadIdx.x & 63;
  const float* p = embed + (size_t)w * D + lane * 8;
  const float4 a = *(const float4*)p;
  const float4 b = *(const float4*)(p + 4);
  float s = a.x * a.x + a.y * a.y + a.z * a.z + a.w * a.w +
            b.x * b.x + b.y * b.y + b.z * b.z + b.w * b.w;
#pragma unroll
  for (int m = 32; m >= 1; m >>= 1) s += __shfl_xor(s, m, 64);
  if (lane == 0) e2[w] = s;
}

// ---------------------------------------------------------------------------
// MFMA distance kernel, 128x128 tile, 256 thr (4 waves 1Mx4N, wave 128x32).
// 2-term split xh*eh + xh*el.  Double-buffered 2x24KB LDS (48 KB total)
// -> 3 blocks/CU so per-tile barrier stalls amortize across blocks
// (R11's 98KB/1-block-per-CU exposed every stall: 37% MfmaUtil).
// Per-CU/tile: MFMA 621 cyc vs LDS ~288 cyc -> MFMA-bound.
// Emits chunkmin at 32-code granularity for the targeted exact recheck.
// ---------------------------------------------------------------------------
__global__ __launch_bounds__(256) void vq_mfma_kernel(
    const uint32_t* __restrict__ xp, const uint32_t* __restrict__ ep,
    const float* __restrict__ e2g, u64* __restrict__ min1g,
    u64* __restrict__ min2g, float* __restrict__ chunkmin) {
  __shared__ __align__(16) char smem[49152];
  // buffer b at b*24576: [0,8K) X-hi | [8K,16K) E-hi | [16K,24K) E-lo

  const int tid  = threadIdx.x;
  const int lane = tid & 63;
  const int wcI  = tid >> 6;           // 0..3 (wave = 32-code column group)
  const int wc   = wcI * 32;

  // XCD swizzle (8192 % 8 == 0 -> bijective); cb fast-varying for L2 reuse:
  // e panel per XCD = 8 cb x 256 KB = 2 MB (L2-resident).
  const int xcd = blockIdx.x & 7;
  const int id  = blockIdx.x >> 3;     // 0..1023
  const int cb  = xcd * 8 + (id & 7);  // 0..63
  const int rb  = id >> 3;             // 0..127
  const int row0 = rb * BM;
  const int c0   = cb * BN;

  const char* xtile = (const char*)xp + (size_t)rb * (NKC * XTILE_B);
  const char* etile = (const char*)ep + (size_t)cb * (NKC * ETILE_B);

  f32x4 acc[8][2];
#pragma unroll
  for (int i = 0; i < 8; ++i)
#pragma unroll
    for (int j = 0; j < 2; ++j) acc[i][j] = (f32x4)0.f;

  const int fr = lane & 15;
  const int cl = lane >> 4;
  const int cs = (cl ^ ((fr >> 1) & 3)) * 16;  // swizzled k-quarter byte off

#define STAGE(kc, b)                                                          \
  do {                                                                        \
    char* lb = smem + (b) * 24576 + tid * 16;                                 \
    const char* gx = xtile + (size_t)(kc) * XTILE_B + tid * 16;               \
    const char* ge = etile + (size_t)(kc) * ETILE_B + tid * 16;               \
    __builtin_amdgcn_global_load_lds((const as1_u32*)(const void*)gx,         \
        (as3_u32*)(void*)lb, 16, 0, 0);                                       \
    __builtin_amdgcn_global_load_lds((const as1_u32*)(const void*)(gx+4096),  \
        (as3_u32*)(void*)(lb + 4096), 16, 0, 0);                              \
    __builtin_amdgcn_global_load_lds((const as1_u32*)(const void*)ge,         \
        (as3_u32*)(void*)(lb + 8192), 16, 0, 0);                              \
    __builtin_amdgcn_global_load_lds((const as1_u32*)(const void*)(ge+4096),  \
        (as3_u32*)(void*)(lb + 12288), 16, 0, 0);                             \
    __builtin_amdgcn_global_load_lds((const as1_u32*)(const void*)(ge+8192),  \
        (as3_u32*)(void*)(lb + 16384), 16, 0, 0);                             \
    __builtin_amdgcn_global_load_lds((const as1_u32*)(const void*)(ge+12288), \
        (as3_u32*)(void*)(lb + 20480), 16, 0, 0);                             \
  } while (0)

  STAGE(0, 0);

  int cur = 0;
  for (int t = 0; t < NKC; ++t) {
    // K-tile boundary: this tile's loads were issued a full tile early.
    asm volatile("s_waitcnt vmcnt(0)" ::: "memory");
    __builtin_amdgcn_s_barrier();
    __builtin_amdgcn_sched_barrier(0);
    asm volatile("" ::: "memory");

    if (t + 1 < NKC) STAGE(t + 1, cur ^ 1);   // in flight across whole tile

    const char* sb = smem + cur * 24576;
    short8 bh[2], bl[2];
#pragma unroll
    for (int j = 0; j < 2; ++j) {
      const int erow = wc + j * 16 + fr;
      bh[j] = *(const short8*)(sb + 8192 + erow * 64 + cs);
      bl[j] = *(const short8*)(sb + 16384 + erow * 64 + cs);
    }
#pragma unroll
    for (int i = 0; i < 8; ++i) {
      const int arow = i * 16 + fr;
      const short8 ah = *(const short8*)(sb + arow * 64 + cs);
      __builtin_amdgcn_s_setprio(1);
#pragma unroll
      for (int j = 0; j < 2; ++j) {
        acc[i][j] = __builtin_amdgcn_mfma_f32_16x16x32_bf16(ah, bh[j], acc[i][j], 0, 0, 0);
        acc[i][j] = __builtin_amdgcn_mfma_f32_16x16x32_bf16(ah, bl[j], acc[i][j], 0, 0, 0);
      }
      __builtin_amdgcn_s_setprio(0);
    }
    cur ^= 1;
  }
#undef STAGE

  // ---- epilogue: per-row top-2 over this block's 128 codes ----
  float e2v[2];
#pragma unroll
  for (int j = 0; j < 2; ++j) e2v[j] = e2g[c0 + wc + j * 16 + fr];

  __syncthreads();                       // all LDS reads done; reuse smem
  u64 (*mb)[4][2] = (u64(*)[4][2])smem;  // [128 rows][4 col-waves][min1,min2]

#pragma unroll
  for (int i = 0; i < 8; ++i) {
#pragma unroll
    for (int r = 0; r < 4; ++r) {
      const float s0 = fmaf(-2.f, acc[i][0][r], e2v[0]);
      const float s1 = fmaf(-2.f, acc[i][1][r], e2v[1]);
      float v1, v2;
      int c1;
      if (s1 < s0) { v1 = s1; v2 = s0; c1 = c0 + wc + 16 + fr; }
      else         { v1 = s0; v2 = s1; c1 = c0 + wc + fr; }
      u64 p1 = ((u64)fkey(v1) << 32) | (uint32_t)c1;
      uint32_t k2 = fkey(v2);
#pragma unroll
      for (int m = 8; m >= 1; m >>= 1) {   // merge across 16-lane row-group
        const u64 o1 = __shfl_xor(p1, m, 64);
        const uint32_t o2 = __shfl_xor(k2, m, 64);
        const u64 lo_ = p1 < o1 ? p1 : o1;
        const u64 hi_ = p1 < o1 ? o1 : p1;
        uint32_t nk = k2 < o2 ? k2 : o2;
        const uint32_t hk = (uint32_t)(hi_ >> 32);
        k2 = nk < hk ? nk : hk;
        p1 = lo_;
      }
      if ((lane & 15) == 0) {
        const int lrow = i * 16 + (lane >> 4) * 4 + r;
        mb[lrow][wcI][0] = p1;
        mb[lrow][wcI][1] = ((u64)k2 << 32) | 0xFFFFFFFFull;
      }
    }
  }
  __syncthreads();

  if (tid < BM) {
    u64 m1 = mb[tid][0][0], m2 = mb[tid][0][1];
    // chunkmin: per (32-code chunk, row), coalesced [chunk][row] layout
    chunkmin[(size_t)(cb * 4 + 0) * NROWS + row0 + tid] =
        unfkey((uint32_t)(mb[tid][0][0] >> 32));
#pragma unroll
    for (int q = 1; q < 4; ++q) {
      const u64 a1 = mb[tid][q][0], a2 = mb[tid][q][1];
      chunkmin[(size_t)(cb * 4 + q) * NROWS + row0 + tid] =
          unfkey((uint32_t)(a1 >> 32));
      const u64 nm1 = m1 < a1 ? m1 : a1;
      const u64 big = m1 < a1 ? a1 : m1;
      u64 nm2 = m2 < a2 ? m2 : a2;
      nm2 = nm2 < big ? nm2 : big;
      m1 = nm1; m2 = nm2;
    }
    // lock-free global top-2 merge
    const u64 old = atomicMin(&min1g[row0 + tid], m1);
    u64 push = m1 < old ? old : m1;       // max(m1, old)
    push = m2 < push ? m2 : push;
    atomicMin(&min2g[row0 + tid], push);
  }
}

// ---------------------------------------------------------------------------
// Flag rows whose approx top-2 gap < EPS (= 2B).
// ---------------------------------------------------------------------------
__global__ __launch_bounds__(256) void vq_flag_kernel(
    const u64* __restrict__ min1g, const u64* __restrict__ min2g,
    int* __restrict__ count, int* __restrict__ list) {
  const int row = blockIdx.x * 256 + threadIdx.x;
  const float f1 = unfkey((uint32_t)(min1g[row] >> 32));
  const float f2 = unfkey((uint32_t)(min2g[row] >> 32));
  if (!(f2 - f1 >= EPS)) {              // also catches NaN
    const int p = atomicAdd(count, 1);
    list[p] = row;
  }
}

// ---------------------------------------------------------------------------
// Targeted exact recheck at 32-code chunk granularity.
// True argmin c* has approx(c*) <= f1 + EPS, so its chunk always passes.
// Result is a PLAIN STORE (single writer) — R10 lesson: atomicMin against
// the negatively-biased approx key keeps wrong indices.
// ---------------------------------------------------------------------------
__global__ __launch_bounds__(256) void vq_exact_kernel(
    const float* __restrict__ x, const float* __restrict__ embed,
    const float* __restrict__ e2g, const int* __restrict__ count,
    const int* __restrict__ list, const float* __restrict__ chunkmin,
    u64* __restrict__ min1g) {
  __shared__ u64 wbest[4];
  const int lane = threadIdx.x & 63;
  const int wv   = threadIdx.x >> 6;

  const int n = *count;
  for (int it = blockIdx.x; it < n; it += RCB) {
    const int row = list[it];
    const float thr = unfkey((uint32_t)(min1g[row] >> 32)) + EPS;

    const float* xpr = x + (size_t)row * D + lane * 8;
    const float4 xa = *(const float4*)xpr;
    const float4 xb = *(const float4*)(xpr + 4);

    float bv = 3.4e38f;
    int   bi = 0x7FFFFFFF;
    for (int g = wv; g < NC32; g += 4) {
      if (chunkmin[(size_t)g * NROWS + row] > thr) continue;  // wave-uniform
      const int cbase = g * 32;
      for (int i = 0; i < 32; ++i) {
        const int c = cbase + i;
        const float* epr = embed + (size_t)c * D + lane * 8;
        const float4 ea = *(const float4*)epr;
        const float4 eb = *(const float4*)(epr + 4);
        float p = xa.x * ea.x + xa.y * ea.y + xa.z * ea.z + xa.w * ea.w +
                  xb.x * eb.x + xb.y * eb.y + xb.z * eb.z + xb.w * eb.w;
#pragma unroll
        for (int m = 32; m >= 1; m >>= 1) p += __shfl_xor(p, m, 64);
        const float s = fmaf(-2.f, p, e2g[c]);
        if (s < bv || (s == bv && c < bi)) { bv = s; bi = c; }
      }
    }
    const u64 pk = ((u64)fkey(bv) << 32) | (uint32_t)bi;
    if (lane == 0) wbest[wv] = pk;
    __syncthreads();
    if (threadIdx.x == 0) {
      u64 m = wbest[0];
#pragma unroll
      for (int q = 1; q < 4; ++q) m = wbest[q] < m ? wbest[q] : m;
      min1g[row] = m;   // exact result REPLACES approx (single writer)
    }
    __syncthreads();
  }
}

// ---------------------------------------------------------------------------
__global__ void vq_finish_kernel(const float* __restrict__ x,
                                 const float* __restrict__ embed,
                                 const u64* __restrict__ min1g,
                                 float* __restrict__ out_q,
                                 float* __restrict__ out_idx,
                                 float* __restrict__ out_loss) {
  const int row  = blockIdx.x * 4 + (threadIdx.x >> 6);
  const int lane = threadIdx.x & 63;
  const int idx  = (int)(min1g[row] & 0xFFFFFFFFull);
  if (lane == 0) out_idx[row] = (float)idx;

  const float* ep = embed + (size_t)idx * D + lane * 8;
  const float* xp = x + (size_t)row * D + lane * 8;
  float* qp       = out_q + (size_t)row * D + lane * 8;

  const float4 e0 = *(const float4*)ep;
  const float4 e1 = *(const float4*)(ep + 4);
  const float4 x0 = *(const float4*)xp;
  const float4 x1 = *(const float4*)(xp + 4);
  *(float4*)qp       = e0;   // x + sg(q - x) == q numerically
  *(float4*)(qp + 4) = e1;

  float l = (e0.x - x0.x) * (e0.x - x0.x) + (e0.y - x0.y) * (e0.y - x0.y) +
            (e0.z - x0.z) * (e0.z - x0.z) + (e0.w - x0.w) * (e0.w - x0.w) +
            (e1.x - x1.x) * (e1.x - x1.x) + (e1.y - x1.y) * (e1.y - x1.y) +
            (e1.z - x1.z) * (e1.z - x1.z) + (e1.w - x1.w) * (e1.w - x1.w);
#pragma unroll
  for (int m = 32; m >= 1; m >>= 1) l += __shfl_xor(l, m, 64);
  if (lane == 0)
    atomicAdd(out_loss, l * (1.f / (float)((size_t)NROWS * D)));
}

// ---------------------------------------------------------------------------
extern "C" void kernel_launch(void* const* d_in, const int* in_sizes, int n_in,
                              void* d_out, int out_size, void* d_ws,
                              size_t ws_size, hipStream_t stream) {
  (void)in_sizes; (void)n_in; (void)out_size; (void)ws_size;
  const float* x     = (const float*)d_in[0];
  const float* embed = (const float*)d_in[1];

  char* ws = (char*)d_ws;
  u64*  min1    = (u64*)ws;                                  // 128 KB
  u64*  min2    = (u64*)(ws + (size_t)NROWS * 8);            // 128 KB
  float* e2     = (float*)(ws + (size_t)NROWS * 16);         // 32 KB
  int*  count   = (int*)(ws + (size_t)NROWS * 16 + NCODES * 4);
  int*  list    = (int*)(ws + (size_t)NROWS * 16 + NCODES * 4 + 16);
  float* chkmin = (float*)(ws + (1u << 20));                 // 16 MB @ 1 MB
  uint32_t* pack_x = (uint32_t*)(ws + (18u << 20));          // 16 MB @ 18 MB
  uint32_t* pack_e = (uint32_t*)(ws + (34u << 20));          // 16 MB @ 34 MB

  float* out_q    = (float*)d_out;                 // [16384][512]
  float* out_idx  = out_q + (size_t)NROWS * D;     // [16384] as float
  float* out_loss = out_idx + NROWS;               // [1]

  hipMemsetAsync(d_ws, 0xFF, (size_t)NROWS * 16, stream);    // min1+min2
  hipMemsetAsync(count, 0, sizeof(int), stream);
  hipMemsetAsync(out_loss, 0, sizeof(float), stream);
  vq_pack_kernel<<<(NROWS + NCODES) * 64 / 256, 256, 0, stream>>>(
      x, embed, pack_x, pack_e);
  vq_e2_kernel<<<NCODES / 4, 256, 0, stream>>>(embed, e2);
  vq_mfma_kernel<<<NBLK, 256, 0, stream>>>(pack_x, pack_e, e2, min1, min2,
                                           chkmin);
  vq_flag_kernel<<<NROWS / 256, 256, 0, stream>>>(min1, min2, count, list);
  vq_exact_kernel<<<RCB, 256, 0, stream>>>(x, embed, e2, count, list, chkmin,
                                           min1);
  vq_finish_kernel<<<NROWS / 4, 256, 0, stream>>>(x, embed, min1, out_q,
                                                  out_idx, out_loss);
}

// Round 13
// 538.615 us; speedup vs baseline: 1.2932x; 1.2932x over previous
//
#include <hip/hip_runtime.h>
#include <hip/hip_fp16.h>
#include <cstdint>
#include <cstddef>

#define D       512
#define NROWS   16384
#define NCODES  8192
#define BM      128
#define BN      128
#define NKC     16              // K-tiles (BK=32 each)
#define NBLK    8192            // (16384/128)*(8192/128)
#define EPS     0.2f            // 2B; fp16 1-term err std ~0.009 -> B=0.1 ~ 11sigma
#define RCB     1024
#define XTILE_B 8192            // packed fp16 x per (blk128,kc)
#define ETILE_B 8192            // packed fp16 e per (blk128,kc)
#define NCH     128             // 64-code chunks per row

typedef __attribute__((ext_vector_type(8))) short short8;  // 8 fp16
typedef __attribute__((ext_vector_type(4))) float f32x4;
typedef unsigned long long u64;
typedef __attribute__((address_space(3))) uint32_t as3_u32;
typedef __attribute__((address_space(1))) uint32_t as1_u32;

// order-preserving fp32 <-> u32 key
__device__ __forceinline__ uint32_t fkey(float f) {
  uint32_t u = __float_as_uint(f);
  return (u & 0x80000000u) ? ~u : (u | 0x80000000u);
}
__device__ __forceinline__ float unfkey(uint32_t k) {
  uint32_t u = (k & 0x80000000u) ? (k & 0x7FFFFFFFu) : ~k;
  return __uint_as_float(u);
}
__device__ __forceinline__ uint32_t pkh(float a, float b) {  // 2xfp16 RN pack
  const uint32_t ua = (uint32_t)__half_as_ushort(__float2half(a));
  const uint32_t ub = (uint32_t)__half_as_ushort(__float2half(b));
  return ua | (ub << 16);
}

// ---------------------------------------------------------------------------
// Pre-pack fp32 -> fp16, output-address-ordered, tile-kc layout.
// Chunk (r, cp) at byte r*64 + cp*16 within an 8KB tile; cp = c ^ ((r>>1)&3)
// (bank swizzle matching the MFMA kernel's b128 frag reads).
// ---------------------------------------------------------------------------
__global__ __launch_bounds__(256) void vq_pack_kernel(
    const float* __restrict__ x, const float* __restrict__ embed,
    uint32_t* __restrict__ px, uint32_t* __restrict__ pe) {
  const int oid  = blockIdx.x * 256 + threadIdx.x;
  const bool isX = oid < NROWS * 64;        // block-uniform split
  const int tt   = isX ? oid : oid - NROWS * 64;
  const float* src = isX ? x : embed;
  uint32_t*    dst = isX ? px : pe;

  const int tile   = tt >> 9;        // (blk,kc): 512 chunks each
  const int within = tt & 511;       // = r*4 + cp
  const int blk = tile >> 4, kc = tile & 15;
  const int r   = within >> 2, cpp = within & 3;
  const int c   = cpp ^ ((r >> 1) & 3);     // source k-quarter

  const float* sp = src + (size_t)(blk * 128 + r) * D + kc * 32 + c * 8;
  const float4 v0 = *(const float4*)sp;
  const float4 v1 = *(const float4*)(sp + 4);
  uint32_t* dp = dst + (size_t)tile * 2048 + within * 4;
  *(uint4*)dp = make_uint4(pkh(v0.x, v0.y), pkh(v0.z, v0.w),
                           pkh(v1.x, v1.y), pkh(v1.z, v1.w));
}

// ---------------------------------------------------------------------------
__global__ void vq_e2_kernel(const float* __restrict__ embed,
                             float* __restrict__ e2) {
  const int w    = (blockIdx.x * blockDim.x + threadIdx.x) >> 6;
  const int lane = threadIdx.x & 63;
  const float* p = embed + (size_t)w * D + lane * 8;
  const float4 a = *(const float4*)p;
  const float4 b = *(const float4*)(p + 4);
  float s = a.x * a.x + a.y * a.y + a.z * a.z + a.w * a.w +
            b.x * b.x + b.y * b.y + b.z * b.z + b.w * b.w;
#pragma unroll
  for (int m = 32; m >= 1; m >>= 1) s += __shfl_xor(s, m, 64);
  if (lane == 0) e2[w] = s;
}

// ---------------------------------------------------------------------------
// MFMA distance kernel: SINGLE-term fp16 (xh*eh, fp32 accumulate).
// 128x128 tile, 4 waves (2Mx2N, wave 64x64 — R7's proven decomposition),
// single 16KB LDS buffer -> ~6 blocks/CU; R7 barrier schedule.
// Emits chunkmin at 64-code granularity; exact global top-2 via atomicMin.
// ---------------------------------------------------------------------------
__global__ __launch_bounds__(256) void vq_mfma_kernel(
    const uint32_t* __restrict__ xp, const uint32_t* __restrict__ ep,
    const float* __restrict__ e2g, u64* __restrict__ min1g,
    u64* __restrict__ min2g, float* __restrict__ chunkmin) {
  __shared__ __align__(16) char smem[16384];   // [0,8K) X-hi | [8K,16K) E-hi

  const int tid  = threadIdx.x;
  const int lane = tid & 63;
  const int w    = tid >> 6;          // 0..3
  const int wr   = (w >> 1) * 64;
  const int wcI  = w & 1;
  const int wc   = wcI * 64;

  // XCD swizzle (8192 % 8 == 0 -> bijective); cb fast-varying for L2 reuse.
  const int xcd = blockIdx.x & 7;
  const int id  = blockIdx.x >> 3;     // 0..1023
  const int cb  = xcd * 8 + (id & 7);  // 0..63
  const int rb  = id >> 3;             // 0..127
  const int row0 = rb * BM;
  const int c0   = cb * BN;

  const char* xtile = (const char*)xp + (size_t)rb * (NKC * XTILE_B);
  const char* etile = (const char*)ep + (size_t)cb * (NKC * ETILE_B);

  f32x4 acc[4][4];
#pragma unroll
  for (int i = 0; i < 4; ++i)
#pragma unroll
    for (int j = 0; j < 4; ++j) acc[i][j] = (f32x4)0.f;

  const int fr = lane & 15;
  const int cl = lane >> 4;
  const int cs = (cl ^ ((fr >> 1) & 3)) * 16;  // swizzled k-quarter byte off

#define STAGE(kc)                                                             \
  do {                                                                        \
    char* lb = smem + tid * 16;                                               \
    const char* gx = xtile + (size_t)(kc) * XTILE_B + tid * 16;               \
    const char* ge = etile + (size_t)(kc) * ETILE_B + tid * 16;               \
    __builtin_amdgcn_global_load_lds((const as1_u32*)(const void*)gx,         \
        (as3_u32*)(void*)lb, 16, 0, 0);                                       \
    __builtin_amdgcn_global_load_lds((const as1_u32*)(const void*)(gx+4096),  \
        (as3_u32*)(void*)(lb + 4096), 16, 0, 0);                              \
    __builtin_amdgcn_global_load_lds((const as1_u32*)(const void*)ge,         \
        (as3_u32*)(void*)(lb + 8192), 16, 0, 0);                              \
    __builtin_amdgcn_global_load_lds((const as1_u32*)(const void*)(ge+4096),  \
        (as3_u32*)(void*)(lb + 12288), 16, 0, 0);                             \
  } while (0)

  for (int kc = 0; kc < NKC; ++kc) {
    if (kc) __syncthreads();           // prev tile fully consumed
    STAGE(kc);
    __syncthreads();                   // drains vmcnt(0): tile visible

    short8 bh[4];
#pragma unroll
    for (int j = 0; j < 4; ++j) {
      const int erow = wc + j * 16 + fr;
      bh[j] = *(const short8*)(smem + 8192 + erow * 64 + cs);
    }
#pragma unroll
    for (int i = 0; i < 4; ++i) {
      const int arow = wr + i * 16 + fr;
      const short8 ah = *(const short8*)(smem + arow * 64 + cs);
      __builtin_amdgcn_s_setprio(1);
#pragma unroll
      for (int j = 0; j < 4; ++j)
        acc[i][j] = __builtin_amdgcn_mfma_f32_16x16x32_f16(ah, bh[j], acc[i][j], 0, 0, 0);
      __builtin_amdgcn_s_setprio(0);
    }
  }
#undef STAGE

  // ---- epilogue: per-row top-2 over this block's 128 codes ----
  float e2v[4];
#pragma unroll
  for (int j = 0; j < 4; ++j) e2v[j] = e2g[c0 + wc + j * 16 + fr];

  __syncthreads();                     // all LDS reads done; reuse smem
  u64 (*mb)[2][2] = (u64(*)[2][2])smem;  // [128 rows][2 col-waves][min1,min2]

#pragma unroll
  for (int i = 0; i < 4; ++i) {
#pragma unroll
    for (int r = 0; r < 4; ++r) {
      float v1 = 3.4e38f, v2 = 3.4e38f;
      int c1 = 0;
#pragma unroll
      for (int j = 0; j < 4; ++j) {   // codes ascend with j: lowest-idx ties
        const float s = fmaf(-2.f, acc[i][j][r], e2v[j]);
        if (s < v1) { v2 = v1; v1 = s; c1 = c0 + wc + j * 16 + fr; }
        else if (s < v2) v2 = s;
      }
      u64 p1 = ((u64)fkey(v1) << 32) | (uint32_t)c1;
      uint32_t k2 = fkey(v2);
#pragma unroll
      for (int m = 8; m >= 1; m >>= 1) {   // merge across 16-lane row-group
        const u64 o1 = __shfl_xor(p1, m, 64);
        const uint32_t o2 = __shfl_xor(k2, m, 64);
        const u64 lo_ = p1 < o1 ? p1 : o1;
        const u64 hi_ = p1 < o1 ? o1 : p1;
        uint32_t nk = k2 < o2 ? k2 : o2;
        const uint32_t hk = (uint32_t)(hi_ >> 32);
        k2 = nk < hk ? nk : hk;
        p1 = lo_;
      }
      if ((lane & 15) == 0) {
        const int lrow = wr + i * 16 + (lane >> 4) * 4 + r;
        mb[lrow][wcI][0] = p1;
        mb[lrow][wcI][1] = ((u64)k2 << 32) | 0xFFFFFFFFull;
      }
    }
  }
  __syncthreads();

  if (tid < BM) {
    const u64 m1a = mb[tid][0][0], m2a = mb[tid][0][1];
    const u64 m1b = mb[tid][1][0], m2b = mb[tid][1][1];
    // chunkmin at 64-code granularity, coalesced [chunk][row] layout
    chunkmin[(size_t)(cb * 2 + 0) * NROWS + row0 + tid] =
        unfkey((uint32_t)(m1a >> 32));
    chunkmin[(size_t)(cb * 2 + 1) * NROWS + row0 + tid] =
        unfkey((uint32_t)(m1b >> 32));
    const u64 m1 = m1a < m1b ? m1a : m1b;
    const u64 big = m1a < m1b ? m1b : m1a;
    u64 m2 = m2a < m2b ? m2a : m2b;
    m2 = m2 < big ? m2 : big;
    // lock-free global top-2 merge
    const u64 old = atomicMin(&min1g[row0 + tid], m1);
    u64 push = m1 < old ? old : m1;       // max(m1, old)
    push = m2 < push ? m2 : push;
    atomicMin(&min2g[row0 + tid], push);
  }
}

// ---------------------------------------------------------------------------
// Flag rows whose approx top-2 gap < EPS (= 2B).
// ---------------------------------------------------------------------------
__global__ __launch_bounds__(256) void vq_flag_kernel(
    const u64* __restrict__ min1g, const u64* __restrict__ min2g,
    int* __restrict__ count, int* __restrict__ list) {
  const int row = blockIdx.x * 256 + threadIdx.x;
  const float f1 = unfkey((uint32_t)(min1g[row] >> 32));
  const float f2 = unfkey((uint32_t)(min2g[row] >> 32));
  if (!(f2 - f1 >= EPS)) {              // also catches NaN
    const int p = atomicAdd(count, 1);
    list[p] = row;
  }
}

// ---------------------------------------------------------------------------
// Targeted exact recheck at 64-code chunk granularity.
// True argmin c* has approx(c*) <= f1 + EPS, so its chunk always passes.
// Result is a PLAIN STORE (single writer) — R10 lesson.
// ---------------------------------------------------------------------------
__global__ __launch_bounds__(256) void vq_exact_kernel(
    const float* __restrict__ x, const float* __restrict__ embed,
    const float* __restrict__ e2g, const int* __restrict__ count,
    const int* __restrict__ list, const float* __restrict__ chunkmin,
    u64* __restrict__ min1g) {
  __shared__ u64 wbest[4];
  const int lane = threadIdx.x & 63;
  const int wv   = threadIdx.x >> 6;

  const int n = *count;
  for (int it = blockIdx.x; it < n; it += RCB) {
    const int row = list[it];
    const float thr = unfkey((uint32_t)(min1g[row] >> 32)) + EPS;

    const float* xpr = x + (size_t)row * D + lane * 8;
    const float4 xa = *(const float4*)xpr;
    const float4 xb = *(const float4*)(xpr + 4);

    float bv = 3.4e38f;
    int   bi = 0x7FFFFFFF;
    for (int g = wv; g < NCH; g += 4) {
      if (chunkmin[(size_t)g * NROWS + row] > thr) continue;  // wave-uniform
      const int cbase = g * 64;
      for (int i = 0; i < 64; ++i) {
        const int c = cbase + i;
        const float* epr = embed + (size_t)c * D + lane * 8;
        const float4 ea = *(const float4*)epr;
        const float4 eb = *(const float4*)(epr + 4);
        float p = xa.x * ea.x + xa.y * ea.y + xa.z * ea.z + xa.w * ea.w +
                  xb.x * eb.x + xb.y * eb.y + xb.z * eb.z + xb.w * eb.w;
#pragma unroll
        for (int m = 32; m >= 1; m >>= 1) p += __shfl_xor(p, m, 64);
        const float s = fmaf(-2.f, p, e2g[c]);
        if (s < bv || (s == bv && c < bi)) { bv = s; bi = c; }
      }
    }
    const u64 pk = ((u64)fkey(bv) << 32) | (uint32_t)bi;
    if (lane == 0) wbest[wv] = pk;
    __syncthreads();
    if (threadIdx.x == 0) {
      u64 m = wbest[0];
#pragma unroll
      for (int q = 1; q < 4; ++q) m = wbest[q] < m ? wbest[q] : m;
      min1g[row] = m;   // exact result REPLACES approx (single writer)
    }
    __syncthreads();
  }
}

// ---------------------------------------------------------------------------
__global__ void vq_finish_kernel(const float* __restrict__ x,
                                 const float* __restrict__ embed,
                                 const u64* __restrict__ min1g,
                                 float* __restrict__ out_q,
                                 float* __restrict__ out_idx,
                                 float* __restrict__ out_loss) {
  const int row  = blockIdx.x * 4 + (threadIdx.x >> 6);
  const int lane = threadIdx.x & 63;
  const int idx  = (int)(min1g[row] & 0xFFFFFFFFull);
  if (lane == 0) out_idx[row] = (float)idx;

  const float* ep = embed + (size_t)idx * D + lane * 8;
  const float* xp = x + (size_t)row * D + lane * 8;
  float* qp       = out_q + (size_t)row * D + lane * 8;

  const float4 e0 = *(const float4*)ep;
  const float4 e1 = *(const float4*)(ep + 4);
  const float4 x0 = *(const float4*)xp;
  const float4 x1 = *(const float4*)(xp + 4);
  *(float4*)qp       = e0;   // x + sg(q - x) == q numerically
  *(float4*)(qp + 4) = e1;

  float l = (e0.x - x0.x) * (e0.x - x0.x) + (e0.y - x0.y) * (e0.y - x0.y) +
            (e0.z - x0.z) * (e0.z - x0.z) + (e0.w - x0.w) * (e0.w - x0.w) +
            (e1.x - x1.x) * (e1.x - x1.x) + (e1.y - x1.y) * (e1.y - x1.y) +
            (e1.z - x1.z) * (e1.z - x1.z) + (e1.w - x1.w) * (e1.w - x1.w);
#pragma unroll
  for (int m = 32; m >= 1; m >>= 1) l += __shfl_xor(l, m, 64);
  if (lane == 0)
    atomicAdd(out_loss, l * (1.f / (float)((size_t)NROWS * D)));
}

// ---------------------------------------------------------------------------
extern "C" void kernel_launch(void* const* d_in, const int* in_sizes, int n_in,
                              void* d_out, int out_size, void* d_ws,
                              size_t ws_size, hipStream_t stream) {
  (void)in_sizes; (void)n_in; (void)out_size; (void)ws_size;
  const float* x     = (const float*)d_in[0];
  const float* embed = (const float*)d_in[1];

  char* ws = (char*)d_ws;
  u64*  min1    = (u64*)ws;                                  // 128 KB
  u64*  min2    = (u64*)(ws + (size_t)NROWS * 8);            // 128 KB
  float* e2     = (float*)(ws + (size_t)NROWS * 16);         // 32 KB
  int*  count   = (int*)(ws + (size_t)NROWS * 16 + NCODES * 4);
  int*  list    = (int*)(ws + (size_t)NROWS * 16 + NCODES * 4 + 16);
  float* chkmin = (float*)(ws + (1u << 20));                 // 8 MB @ 1 MB
  uint32_t* pack_x = (uint32_t*)(ws + (10u << 20));          // 16 MB @ 10 MB
  uint32_t* pack_e = (uint32_t*)(ws + (26u << 20));          // 8 MB @ 26 MB

  float* out_q    = (float*)d_out;                 // [16384][512]
  float* out_idx  = out_q + (size_t)NROWS * D;     // [16384] as float
  float* out_loss = out_idx + NROWS;               // [1]

  hipMemsetAsync(d_ws, 0xFF, (size_t)NROWS * 16, stream);    // min1+min2
  hipMemsetAsync(count, 0, sizeof(int), stream);
  hipMemsetAsync(out_loss, 0, sizeof(float), stream);
  vq_pack_kernel<<<(NROWS + NCODES) * 64 / 256, 256, 0, stream>>>(
      x, embed, pack_x, pack_e);
  vq_e2_kernel<<<NCODES / 4, 256, 0, stream>>>(embed, e2);
  vq_mfma_kernel<<<NBLK, 256, 0, stream>>>(pack_x, pack_e, e2, min1, min2,
                                           chkmin);
  vq_flag_kernel<<<NROWS / 256, 256, 0, stream>>>(min1, min2, count, list);
  vq_exact_kernel<<<RCB, 256, 0, stream>>>(x, embed, e2, count, list, chkmin,
                                           min1);
  vq_finish_kernel<<<NROWS / 4, 256, 0, stream>>>(x, embed, min1, out_q,
                                                  out_idx, out_loss);
}